// Round 10
// baseline (244.942 us; speedup 1.0000x reference)
//
#include <hip/hip_runtime.h>

#define NB 4
#define NC 8
#define NLOC 524288        // H*W*D
#define TOPN 512
#define POST 100
#define SELBINS 4096
#define SCAP 2048
#define GBX 512            // gather blocks per image
#define WPI 2048           // waves per image (512 blocks x 4 waves)
#define SLOTW 16
#define KEYSPAN (WPI*SLOTW)   // 32768 keys/image
#define FB_CAP 16384
#define NMS_THR 0.6f
#define CAND_THR 0.05f

typedef unsigned long long ull;

// ---------------- workspace (keys/ovf fully rewritten each call; ctr memset) ----------------
// [0,64)                    ctr (u32, memset each call)
// [64, 64+NB*WPI*4)         ovf_arr
// [32832, 32832+NB*KEYSPAN*8) keys (zero-sentinel padded)
#define OFF_CTR  0
#define OFF_OVF  64
#define OFF_KEYS (64 + NB*WPI*4)

__device__ __forceinline__ float sigmoidf_(float x) {
    return 1.0f / (1.0f + __expf(-x));
}

// sparse keys: score>0.5 -> hi in (0x3F000000,0x3F800000]; dense (fallback): >0.05
__device__ __forceinline__ int binof_(ull k, bool dn) {
    const unsigned hi = (unsigned)(k >> 32);
    const int off = (int)hi - (dn ? 0x3D000000 : 0x3F000000);
    int bin = dn ? (off >> 14) : (off >> 11);
    if (off < 0) bin = 0;
    if (bin > SELBINS - 1) bin = SELBINS - 1;
    return bin;
}

__device__ __forceinline__ float iou3d_(const float* a, const float* bx) {
    const float ix = fminf(a[3], bx[3]) - fmaxf(a[0], bx[0]);
    const float iy = fminf(a[4], bx[4]) - fmaxf(a[1], bx[1]);
    const float iz = fminf(a[5], bx[5]) - fmaxf(a[2], bx[2]);
    const float inter = fmaxf(ix, 0.0f) * fmaxf(iy, 0.0f) * fmaxf(iz, 0.0f);
    const float v0 = fmaxf(a[3] - a[0], 0.0f) * fmaxf(a[4] - a[1], 0.0f) * fmaxf(a[5] - a[2], 0.0f);
    const float v1 = fmaxf(bx[3] - bx[0], 0.0f) * fmaxf(bx[4] - bx[1], 0.0f) * fmaxf(bx[5] - bx[2], 0.0f);
    return inter / (v0 + v1 - inter + 1e-9f);
}

// exact fallback rebuild (block-uniform; ~never runs). 256-thread version.
__device__ void rebuild_(const float* __restrict__ cls, const float* __restrict__ ctr,
                         ull* __restrict__ kb, int b, int t,
                         unsigned* hist, unsigned* lpos, int* cut_s, int* md_s, int* dense_s) {
    for (int i = t; i < SELBINS; i += 256) hist[i] = 0;
    if (t == 0) *lpos = 0;
    __syncthreads();
    for (int n = t; n < NLOC; n += 256) {
        const float scv = sigmoidf_(ctr[(size_t)b * NLOC + n]);
        #pragma unroll
        for (int cc = 0; cc < NC; ++cc) {
            const float x = cls[((size_t)b * NC + cc) * NLOC + n];
            if (x > -2.9444390f) {                        // sigmoid(x) > 0.05 pre-gate
                const float s = sigmoidf_(x);
                if (s > CAND_THR) {
                    const ull key = ((ull)__float_as_uint(s * scv) << 32) |
                                    (unsigned)(~(unsigned)(n * NC + cc));
                    atomicAdd(&hist[binof_(key, true)], 1u);
                }
            }
        }
    }
    __syncthreads();
    if (t == 0) {
        unsigned cum = 0; int bin = 0;
        for (int i = SELBINS - 1; i >= 0; --i) {
            cum += hist[i];
            if (cum >= (unsigned)TOPN) { bin = i; break; }
        }
        *cut_s = bin;
    }
    __syncthreads();
    const int cb = *cut_s;
    for (int n = t; n < NLOC; n += 256) {
        const float scv = sigmoidf_(ctr[(size_t)b * NLOC + n]);
        #pragma unroll
        for (int cc = 0; cc < NC; ++cc) {
            const float x = cls[((size_t)b * NC + cc) * NLOC + n];
            if (x > -2.9444390f) {
                const float s = sigmoidf_(x);
                if (s > CAND_THR) {
                    const ull key = ((ull)__float_as_uint(s * scv) << 32) |
                                    (unsigned)(~(unsigned)(n * NC + cc));
                    if (binof_(key, true) >= cb) {
                        const unsigned pos = atomicAdd(lpos, 1u);
                        if (pos < (unsigned)FB_CAP) kb[pos] = key;
                    }
                }
            }
        }
    }
    __syncthreads();
    if (t == 0) {
        *md_s = (int)((*lpos < (unsigned)FB_CAP) ? *lpos : (unsigned)FB_CAP);
        *dense_s = 1;
    }
    __syncthreads();
}

// ---------------- THE kernel: gather (all blocks) -> grid barrier -> tail (4 blocks) ----------------
__global__ __launch_bounds__(256, 4) void fused_all(const float* __restrict__ cls,
                                                    const float* __restrict__ ctr,
                                                    const float* __restrict__ loc,
                                                    const float* __restrict__ box,
                                                    ull* __restrict__ keys,
                                                    unsigned* __restrict__ ovf_arr,
                                                    unsigned* __restrict__ ctrp,
                                                    float* __restrict__ out) {
    __shared__ union SU {
        unsigned hist[SELBINS];                                   // 16KB (select + rebuild)
        ull surv[SCAP];                                           // 16KB
        struct { float sd[TOPN * 6]; float ss[TOPN];
                 unsigned char scl[TOPN]; unsigned char keep[TOPN];
                 short clist[NC][128]; } nms;                     // ~17KB
    } u;
    __shared__ ull tkl[TOPN];                                     // 4KB
    __shared__ unsigned redo_[4];
    __shared__ unsigned scnt, tot_s, lpos;
    __shared__ int cut_s, dense_s, md_s, chcnt[NC];

    const int b = blockIdx.y;
    const int t = threadIdx.x, lane = t & 63, wid = t >> 6;
    const ull lt = (1ull << lane) - 1ull;

    // ================= gather (every block; no LDS/atomics/barriers) =================
    {
        const int n0 = (blockIdx.x * 256 + t) * 4;
        const float4 cv = *(const float4*)(ctr + (size_t)b * NLOC + n0);
        float4 cl[NC];
        #pragma unroll
        for (int c = 0; c < NC; ++c)
            cl[c] = *(const float4*)(cls + ((size_t)b * NC + c) * NLOC + n0);

        unsigned hm = 0;
        #pragma unroll
        for (int j = 0; j < 4; ++j)
            #pragma unroll
            for (int c = 0; c < NC; ++c)
                if (((const float*)&cl[c])[j] > 0.0f) hm |= 1u << (j * 8 + c);

        ull k0 = 0, k1 = 0, k2 = 0, k3 = 0;
        int kc = 0;
        if (hm) {
            #pragma unroll
            for (int j = 0; j < 4; ++j) {
                if ((hm >> (j * 8)) & 0xffu) {
                    const float sc = sigmoidf_(((const float*)&cv)[j]);
                    #pragma unroll
                    for (int c = 0; c < NC; ++c) {
                        if ((hm >> (j * 8 + c)) & 1u) {
                            const float p = sigmoidf_(((const float*)&cl[c])[j]) * sc;
                            if (p > 0.5f) {
                                const unsigned flat = (unsigned)((n0 + j) * NC + c);
                                const ull key = ((ull)__float_as_uint(p) << 32) | (unsigned)(~flat);
                                if (kc == 0) k0 = key;
                                else if (kc == 1) k1 = key;
                                else if (kc == 2) k2 = key;
                                else if (kc == 3) k3 = key;
                                ++kc;
                            }
                        }
                    }
                }
            }
        }
        const ull m1 = __ballot(kc >= 1), m2 = __ballot(kc >= 2);
        const ull m3 = __ballot(kc >= 3), m4 = __ballot(kc >= 4);
        const unsigned pos = (unsigned)(__popcll(m1 & lt) + __popcll(m2 & lt) +
                                        __popcll(m3 & lt) + __popcll(m4 & lt));
        const unsigned tot = (unsigned)(__popcll(m1) + __popcll(m2) + __popcll(m3) + __popcll(m4));
        const ull mo = __ballot(kc > 4);
        const int wgid = blockIdx.x * 4 + wid;
        ull* kb = keys + ((size_t)b * WPI + wgid) * SLOTW;
        const int sc_ = (kc > 4) ? 4 : kc;
        if (sc_ >= 1 && pos + 0 < SLOTW) kb[pos + 0] = k0;
        if (sc_ >= 2 && pos + 1 < SLOTW) kb[pos + 1] = k1;
        if (sc_ >= 3 && pos + 2 < SLOTW) kb[pos + 2] = k2;
        if (sc_ >= 4 && pos + 3 < SLOTW) kb[pos + 3] = k3;
        const unsigned zstart = (tot > (unsigned)SLOTW) ? (unsigned)SLOTW : tot;
        if (lane >= 48) {
            const unsigned s = (unsigned)(lane - 48);
            if (s >= zstart) kb[s] = 0;
        }
        if (lane == 0)
            ovf_arr[b * WPI + wgid] = ((tot > (unsigned)SLOTW) || mo) ? 1u : 0u;
    }
    __syncthreads();
    if (t == 0) {
        __threadfence();
        __hip_atomic_fetch_add(ctrp, 1u, __ATOMIC_RELEASE, __HIP_MEMORY_SCOPE_AGENT);
    }
    if (blockIdx.x != 0) return;              // only 4 tail blocks ever wait -> no deadlock
    if (t == 0) {
        while (__hip_atomic_load(ctrp, __ATOMIC_ACQUIRE, __HIP_MEMORY_SCOPE_AGENT) <
               (unsigned)(NB * GBX))
            __builtin_amdgcn_s_sleep(2);
    }
    __syncthreads();

    // ================= tail (1 block per image, 256 threads) =================
    ull* kb = keys + (size_t)b * KEYSPAN;

    // A: overflow reduce + tk init
    {
        unsigned o = 0;
        for (int i = t; i < WPI; i += 256) o |= ovf_arr[b * WPI + i];
        #pragma unroll
        for (int d = 32; d >= 1; d >>= 1) o |= __shfl_down(o, d);
        if (lane == 0) redo_[wid] = o;
    }
    for (int i = t; i < TOPN; i += 256) tkl[i] = 0;
    __syncthreads();
    if (t == 0) {
        dense_s = (redo_[0] | redo_[1] | redo_[2] | redo_[3]) ? 1 : 0;
        md_s = 0;
    }
    __syncthreads();
    if (dense_s) rebuild_(cls, ctr, kb, b, t, u.hist, &lpos, &cut_s, &md_s, &dense_s);

    // B/C: histogram + cutoff (retry once via rebuild if total < 512)
    for (int pass = 0; pass < 2; ++pass) {
        for (int i = t; i < SELBINS; i += 256) u.hist[i] = 0;
        if (t == 0) scnt = 0;
        __syncthreads();
        {
            const bool dn = (dense_s != 0);
            const int Md = md_s;
            for (int r = 0; r < KEYSPAN / 2048; ++r) {        // 16 rounds x 8 unrolled loads
                ull v[8];
                #pragma unroll
                for (int q = 0; q < 8; ++q) v[q] = kb[r * 2048 + q * 256 + t];
                #pragma unroll
                for (int q = 0; q < 8; ++q) {
                    const int g = r * 2048 + q * 256 + t;
                    const bool pred = dn ? (g < Md) : (v[q] != 0ull);
                    if (pred) atomicAdd(&u.hist[binof_(v[q], dn)], 1u);
                }
            }
        }
        __syncthreads();
        if (t < 64) {
            unsigned s = 0;
            #pragma unroll 8
            for (int i = 0; i < 64; ++i)
                s += u.hist[t * 64 + ((i + t) & 63)];
            unsigned suf = s;
            #pragma unroll
            for (int d = 1; d < 64; d <<= 1) {
                const unsigned o2 = __shfl_down(suf, d);
                suf += (t + d < 64) ? o2 : 0u;
            }
            if (t == 0) tot_s = suf;
            const ull mask = __ballot(suf >= TOPN);
            unsigned nxt = __shfl_down(suf, 1);
            if (t == 63) nxt = 0;
            if (mask == 0ull) {
                if (t == 0) cut_s = 0;
            } else {
                const int L = 63 - __builtin_clzll(mask);
                if (t == L) {
                    unsigned cum = nxt;
                    int c = L * 64;
                    for (int i = 63; i >= 0; --i) {
                        cum += u.hist[L * 64 + i];
                        if (cum >= TOPN) { c = L * 64 + i; break; }
                    }
                    cut_s = c;
                }
            }
        }
        __syncthreads();
        if (tot_s >= (unsigned)TOPN || dense_s) break;
        rebuild_(cls, ctr, kb, b, t, u.hist, &lpos, &cut_s, &md_s, &dense_s);
    }

    // D: wave-aggregated compact into surv (hist dead -> union reuse)
    {
        const bool dn = (dense_s != 0);
        const int Md = md_s;
        const int cb = cut_s;
        __syncthreads();
        for (int r = 0; r < KEYSPAN / 2048; ++r) {
            ull v[8];
            #pragma unroll
            for (int q = 0; q < 8; ++q) v[q] = kb[r * 2048 + q * 256 + t];
            #pragma unroll
            for (int q = 0; q < 8; ++q) {
                const int g = r * 2048 + q * 256 + t;
                bool pred = dn ? (g < Md) : (v[q] != 0ull);
                pred = pred && (binof_(v[q], dn) >= cb);
                const ull mv = __ballot(pred);
                unsigned base = 0;
                if (lane == 0 && mv) base = atomicAdd(&scnt, (unsigned)__popcll(mv));
                base = __shfl(base, 0);
                if (pred) {
                    const unsigned pos = base + (unsigned)__popcll(mv & lt);
                    if (pos < (unsigned)SCAP) u.surv[pos] = v[q];
                }
            }
        }
    }
    __syncthreads();

    // E: exact rank-count among survivors -> tkl (sorted desc)
    const unsigned sc_f = scnt;
    if (sc_f <= (unsigned)SCAP) {
        const int S = (int)sc_f;
        for (int i = t; i < S; i += 256) {
            const ull ke = u.surv[i];
            int r = 0;
            int j = 0;
            for (; j + 8 <= S; j += 8) {
                #pragma unroll
                for (int q = 0; q < 8; ++q) r += (u.surv[j + q] > ke) ? 1 : 0;
            }
            for (; j < S; ++j) r += (u.surv[j] > ke) ? 1 : 0;
            if (r < TOPN) tkl[r] = ke;
        }
    } else {
        // pathological tie storm: exact global rank-count (never on this data)
        const bool dn = (dense_s != 0);
        const int Md = md_s;
        for (int i = t; i < KEYSPAN; i += 256) {
            const ull k = kb[i];
            const bool v = dn ? (i < Md) : (k != 0ull);
            if (!v) continue;
            int r = 0;
            for (int j = 0; j < KEYSPAN; ++j) {
                const ull kj = kb[j];
                const bool vj = dn ? (j < Md) : (kj != 0ull);
                r += (vj && kj > k) ? 1 : 0;
            }
            if (r < TOPN) tkl[r] = k;
        }
    }
    __syncthreads();

    // F: decode (2 slots/thread; surv dead -> nms union live)
    #pragma unroll
    for (int half = 0; half < 2; ++half) {
        const int s_ = half * 256 + t;
        const ull k = tkl[s_];
        const unsigned bits = (unsigned)(k >> 32);
        const float val = __uint_as_float(bits);
        const unsigned flat = ~(unsigned)(k & 0xffffffffu);
        int n = 0, c = 0;
        if (val > 0.0f) { n = (int)(flat >> 3); c = (int)(flat & 7u); }
        const float lx = loc[n * 3 + 0], ly = loc[n * 3 + 1], lz = loc[n * 3 + 2];
        const float* bp = box + (size_t)b * 6 * NLOC + n;
        const float b0 = bp[0];
        const float b1 = bp[(size_t)NLOC];
        const float b2 = bp[2 * (size_t)NLOC];
        const float b3 = bp[3 * (size_t)NLOC];
        const float b4 = bp[4 * (size_t)NLOC];
        const float b5 = bp[5 * (size_t)NLOC];
        const float d0 = fminf(fmaxf(lx - b0, 0.0f), 255.0f);
        const float d1 = fminf(fmaxf(ly - b1, 0.0f), 255.0f);
        const float d2 = fminf(fmaxf(lz - b2, 0.0f), 63.0f);
        const float d3 = fminf(fmaxf(lx + b3, 0.0f), 255.0f);
        const float d4 = fminf(fmaxf(ly + b4, 0.0f), 255.0f);
        const float d5 = fminf(fmaxf(lz + b5, 0.0f), 63.0f);
        const bool ok = (d3 - d0 >= 0.0f) && (d4 - d1 >= 0.0f) && (d5 - d2 >= 0.0f);
        u.nms.sd[s_ * 6 + 0] = d0; u.nms.sd[s_ * 6 + 1] = d1; u.nms.sd[s_ * 6 + 2] = d2;
        u.nms.sd[s_ * 6 + 3] = d3; u.nms.sd[s_ * 6 + 4] = d4; u.nms.sd[s_ * 6 + 5] = d5;
        u.nms.ss[s_] = (val > 0.0f) ? sqrtf(val) : 0.0f;
        u.nms.scl[s_] = (unsigned char)(c + 1);
        u.nms.keep[s_] = ((val > 0.0f) && ok) ? 1 : 0;
    }
    __syncthreads();

    // G: per-class NMS; wave w handles classes w+1 and w+5
    for (int qq = 0; qq < 2; ++qq) {
        const int mycls = wid + 1 + 4 * qq;
        const float* sd = u.nms.sd;
        int cnt = 0;
        for (int j0 = 0; j0 < TOPN; j0 += 64) {
            const int j = j0 + lane;
            const bool pred = ((int)u.nms.scl[j] == mycls) && (u.nms.keep[j] != 0);
            const ull m = __ballot(pred);
            if (pred) {
                const int pos = cnt + __popcll(m & lt);
                if (pos < 128) u.nms.clist[wid][pos] = (short)j;
            }
            cnt += __popcll(m);
        }
        if (cnt <= 128) {
            const bool h0 = (lane < cnt), h1 = (lane + 64 < cnt);
            const int g0 = h0 ? u.nms.clist[wid][lane] : 0;
            const int g1 = h1 ? u.nms.clist[wid][lane + 64] : 0;
            float A0[6], A1[6];
            #pragma unroll
            for (int q = 0; q < 6; ++q) {
                A0[q] = h0 ? sd[g0 * 6 + q] : 0.0f;
                A1[q] = h1 ? sd[g1 * 6 + q] : 0.0f;
            }
            ull s0 = 0, s1lo = 0, s1hi = 0;
            for (int i = 0; i < cnt; ++i) {
                const int gi = u.nms.clist[wid][i];
                float pb[6];
                #pragma unroll
                for (int q = 0; q < 6; ++q) pb[q] = sd[gi * 6 + q];
                if (i < 64) {
                    if (h0 && lane > i && iou3d_(A0, pb) > NMS_THR) s0 |= 1ull << i;
                    if (h1 && iou3d_(A1, pb) > NMS_THR) s1lo |= 1ull << i;
                } else {
                    if (h1 && (i - 64) < lane && iou3d_(A1, pb) > NMS_THR) s1hi |= 1ull << (i - 64);
                }
            }
            bool a0 = h0, a1 = h1;
            ull m0 = __ballot(a0), m1 = __ballot(a1);
            for (int i = 0; i < cnt; ++i) {
                const bool alive_i = (i < 64) ? ((m0 >> i) & 1ull) : ((m1 >> (i - 64)) & 1ull);
                if (!alive_i) continue;
                if (a0 && i < 64 && ((s0 >> i) & 1ull)) a0 = false;
                if (a1) {
                    const bool sb = (i < 64) ? ((s1lo >> i) & 1ull) : ((s1hi >> (i - 64)) & 1ull);
                    if (sb) a1 = false;
                }
                m0 = __ballot(a0); m1 = __ballot(a1);
            }
            if (h0 && !a0) u.nms.keep[g0] = 0;
            if (h1 && !a1) u.nms.keep[g1] = 0;
        } else {
            // general greedy over raw slots (adversarial class skew only)
            volatile unsigned char* vkeep = u.nms.keep;
            for (int i = 0; i < TOPN; ++i) {
                if ((int)u.nms.scl[i] != mycls || !vkeep[i]) continue;
                float pb[6];
                #pragma unroll
                for (int q = 0; q < 6; ++q) pb[q] = sd[i * 6 + q];
                for (int e = i + 1 + lane; e < TOPN; e += 64) {
                    if ((int)u.nms.scl[e] == mycls && vkeep[e]) {
                        float cbx[6];
                        #pragma unroll
                        for (int q = 0; q < 6; ++q) cbx[q] = sd[e * 6 + q];
                        if (iou3d_(cbx, pb) > NMS_THR) vkeep[e] = 0;
                    }
                }
                __threadfence_block();
            }
        }
    }
    __syncthreads();

    // H: rank survivors in slot order, emit top-100
    #pragma unroll
    for (int half = 0; half < 2; ++half) {
        const int s_ = half * 256 + t;
        const ull m = __ballot(u.nms.keep[s_] != 0);
        if (lane == 0) chcnt[half * 4 + wid] = __popcll(m);
    }
    __syncthreads();
    {
        int total = 0;
        #pragma unroll
        for (int c = 0; c < NC; ++c) total += chcnt[c];
        const int tc = (total < POST) ? total : POST;
        float* fbox = out;                       // (B,100,6)
        float* fscore = out + NB * POST * 6;     // (B,100)
        float* flabel = out + NB * POST * 7;     // (B,100)
        float* fvalid = out + NB * POST * 8;     // (B,100)
        #pragma unroll
        for (int half = 0; half < 2; ++half) {
            const int s_ = half * 256 + t;
            const int chunk = half * 4 + wid;
            const ull m = __ballot(u.nms.keep[s_] != 0);
            int before = 0;
            for (int c = 0; c < chunk; ++c) before += chcnt[c];
            const int myrank = before + __popcll(m & lt);
            if (u.nms.keep[s_] && myrank < POST) {
                #pragma unroll
                for (int q = 0; q < 6; ++q)
                    fbox[(b * POST + myrank) * 6 + q] = u.nms.sd[s_ * 6 + q];
                fscore[b * POST + myrank] = u.nms.ss[s_];
                flabel[b * POST + myrank] = (float)u.nms.scl[s_];
                fvalid[b * POST + myrank] = 1.0f;
            }
            if (s_ >= tc && s_ < POST) {
                #pragma unroll
                for (int q = 0; q < 6; ++q) fbox[(b * POST + s_) * 6 + q] = 0.0f;
                fscore[b * POST + s_] = 0.0f;
                flabel[b * POST + s_] = 0.0f;
                fvalid[b * POST + s_] = 0.0f;
            }
        }
    }
}

extern "C" void kernel_launch(void* const* d_in, const int* in_sizes, int n_in,
                              void* d_out, int out_size, void* d_ws, size_t ws_size,
                              hipStream_t stream) {
    const float* location = (const float*)d_in[0];
    const float* cls_pred = (const float*)d_in[1];
    const float* box_pred = (const float*)d_in[2];
    const float* ctr_pred = (const float*)d_in[3];

    char* ws = (char*)d_ws;
    unsigned* ctrp = (unsigned*)(ws + OFF_CTR);
    unsigned* ovf  = (unsigned*)(ws + OFF_OVF);
    ull*      keys = (ull*)(ws + OFF_KEYS);

    hipMemsetAsync(ws + OFF_CTR, 0, 64, stream);
    fused_all<<<dim3(GBX, NB), 256, 0, stream>>>(cls_pred, ctr_pred, location, box_pred,
                                                 keys, ovf, ctrp, (float*)d_out);
}

// Round 11
// 203.670 us; speedup vs baseline: 1.2026x; 1.2026x over previous
//
#include <hip/hip_runtime.h>

#define NB 4
#define NC 8
#define NLOC 524288        // H*W*D
#define TOPN 512
#define POST 100
#define SELBINS 4096
#define SCAP 2048
#define GBX 512            // gather blocks per image
#define NSTR 16            // counter stripes per image (each on own 64B line)
#define WPI 2048           // waves per image (512 blocks x 4 waves)
#define SLOTW 16
#define KEYSPAN (WPI*SLOTW)   // 32768 keys/image
#define FB_CAP 16384
#define NMS_THR 0.6f
#define CAND_THR 0.05f

typedef unsigned long long ull;

// ---------------- workspace (keys/ovf fully rewritten each call; counters memset) ----------------
// [0, 4096)                     ctrs: NB*NSTR u32, 64B-strided (memset each call)
// [4096, 4096+NB*WPI*4)         ovf_arr
// [36864, 36864+NB*KEYSPAN*8)   keys (zero-sentinel padded)
#define OFF_CTR  0
#define OFF_OVF  4096
#define OFF_KEYS (4096 + NB*WPI*4)

__device__ __forceinline__ float sigmoidf_(float x) {
    return 1.0f / (1.0f + __expf(-x));
}

// sparse keys: score>0.5 -> hi in (0x3F000000,0x3F800000]; dense (fallback): >0.05
__device__ __forceinline__ int binof_(ull k, bool dn) {
    const unsigned hi = (unsigned)(k >> 32);
    const int off = (int)hi - (dn ? 0x3D000000 : 0x3F000000);
    int bin = dn ? (off >> 14) : (off >> 11);
    if (off < 0) bin = 0;
    if (bin > SELBINS - 1) bin = SELBINS - 1;
    return bin;
}

__device__ __forceinline__ float iou3d_(const float* a, const float* bx) {
    const float ix = fminf(a[3], bx[3]) - fmaxf(a[0], bx[0]);
    const float iy = fminf(a[4], bx[4]) - fmaxf(a[1], bx[1]);
    const float iz = fminf(a[5], bx[5]) - fmaxf(a[2], bx[2]);
    const float inter = fmaxf(ix, 0.0f) * fmaxf(iy, 0.0f) * fmaxf(iz, 0.0f);
    const float v0 = fmaxf(a[3] - a[0], 0.0f) * fmaxf(a[4] - a[1], 0.0f) * fmaxf(a[5] - a[2], 0.0f);
    const float v1 = fmaxf(bx[3] - bx[0], 0.0f) * fmaxf(bx[4] - bx[1], 0.0f) * fmaxf(bx[5] - bx[2], 0.0f);
    return inter / (v0 + v1 - inter + 1e-9f);
}

// exact fallback rebuild (block-uniform; ~never runs). 256-thread version.
__device__ void rebuild_(const float* __restrict__ cls, const float* __restrict__ ctr,
                         ull* __restrict__ kb, int b, int t,
                         unsigned* hist, unsigned* lpos, int* cut_s, int* md_s, int* dense_s) {
    for (int i = t; i < SELBINS; i += 256) hist[i] = 0;
    if (t == 0) *lpos = 0;
    __syncthreads();
    for (int n = t; n < NLOC; n += 256) {
        const float scv = sigmoidf_(ctr[(size_t)b * NLOC + n]);
        #pragma unroll
        for (int cc = 0; cc < NC; ++cc) {
            const float x = cls[((size_t)b * NC + cc) * NLOC + n];
            if (x > -2.9444390f) {                        // sigmoid(x) > 0.05 pre-gate
                const float s = sigmoidf_(x);
                if (s > CAND_THR) {
                    const ull key = ((ull)__float_as_uint(s * scv) << 32) |
                                    (unsigned)(~(unsigned)(n * NC + cc));
                    atomicAdd(&hist[binof_(key, true)], 1u);
                }
            }
        }
    }
    __syncthreads();
    if (t == 0) {
        unsigned cum = 0; int bin = 0;
        for (int i = SELBINS - 1; i >= 0; --i) {
            cum += hist[i];
            if (cum >= (unsigned)TOPN) { bin = i; break; }
        }
        *cut_s = bin;
    }
    __syncthreads();
    const int cb = *cut_s;
    for (int n = t; n < NLOC; n += 256) {
        const float scv = sigmoidf_(ctr[(size_t)b * NLOC + n]);
        #pragma unroll
        for (int cc = 0; cc < NC; ++cc) {
            const float x = cls[((size_t)b * NC + cc) * NLOC + n];
            if (x > -2.9444390f) {
                const float s = sigmoidf_(x);
                if (s > CAND_THR) {
                    const ull key = ((ull)__float_as_uint(s * scv) << 32) |
                                    (unsigned)(~(unsigned)(n * NC + cc));
                    if (binof_(key, true) >= cb) {
                        const unsigned pos = atomicAdd(lpos, 1u);
                        if (pos < (unsigned)FB_CAP) kb[pos] = key;
                    }
                }
            }
        }
    }
    __syncthreads();
    if (t == 0) {
        *md_s = (int)((*lpos < (unsigned)FB_CAP) ? *lpos : (unsigned)FB_CAP);
        *dense_s = 1;
    }
    __syncthreads();
}

// ---------------- THE kernel: gather (all blocks) -> striped grid barrier -> tail (4 blocks) ----------------
__global__ __launch_bounds__(256, 4) void fused_all(const float* __restrict__ cls,
                                                    const float* __restrict__ ctr,
                                                    const float* __restrict__ loc,
                                                    const float* __restrict__ box,
                                                    ull* __restrict__ keys,
                                                    unsigned* __restrict__ ovf_arr,
                                                    unsigned* __restrict__ ctrp,
                                                    float* __restrict__ out) {
    __shared__ union SU {
        unsigned hist[SELBINS];                                   // 16KB (select + rebuild)
        ull surv[SCAP];                                           // 16KB
        struct { float sd[TOPN * 6]; float ss[TOPN];
                 unsigned char scl[TOPN]; unsigned char keep[TOPN];
                 short clist[NC][128]; } nms;                     // ~17KB
    } u;
    __shared__ ull tkl[TOPN];                                     // 4KB
    __shared__ unsigned redo_[4];
    __shared__ unsigned scnt, tot_s, lpos;
    __shared__ int cut_s, dense_s, md_s, chcnt[NC];

    const int b = blockIdx.y;
    const int t = threadIdx.x, lane = t & 63, wid = t >> 6;
    const ull lt = (1ull << lane) - 1ull;

    // ================= gather (every block; no LDS/atomics/barriers) =================
    {
        const int n0 = (blockIdx.x * 256 + t) * 4;
        const float4 cv = *(const float4*)(ctr + (size_t)b * NLOC + n0);
        float4 cl[NC];
        #pragma unroll
        for (int c = 0; c < NC; ++c)
            cl[c] = *(const float4*)(cls + ((size_t)b * NC + c) * NLOC + n0);

        unsigned hm = 0;
        #pragma unroll
        for (int j = 0; j < 4; ++j)
            #pragma unroll
            for (int c = 0; c < NC; ++c)
                if (((const float*)&cl[c])[j] > 0.0f) hm |= 1u << (j * 8 + c);

        ull k0 = 0, k1 = 0, k2 = 0, k3 = 0;
        int kc = 0;
        if (hm) {
            #pragma unroll
            for (int j = 0; j < 4; ++j) {
                if ((hm >> (j * 8)) & 0xffu) {
                    const float sc = sigmoidf_(((const float*)&cv)[j]);
                    #pragma unroll
                    for (int c = 0; c < NC; ++c) {
                        if ((hm >> (j * 8 + c)) & 1u) {
                            const float p = sigmoidf_(((const float*)&cl[c])[j]) * sc;
                            if (p > 0.5f) {
                                const unsigned flat = (unsigned)((n0 + j) * NC + c);
                                const ull key = ((ull)__float_as_uint(p) << 32) | (unsigned)(~flat);
                                if (kc == 0) k0 = key;
                                else if (kc == 1) k1 = key;
                                else if (kc == 2) k2 = key;
                                else if (kc == 3) k3 = key;
                                ++kc;
                            }
                        }
                    }
                }
            }
        }
        const ull m1 = __ballot(kc >= 1), m2 = __ballot(kc >= 2);
        const ull m3 = __ballot(kc >= 3), m4 = __ballot(kc >= 4);
        const unsigned pos = (unsigned)(__popcll(m1 & lt) + __popcll(m2 & lt) +
                                        __popcll(m3 & lt) + __popcll(m4 & lt));
        const unsigned tot = (unsigned)(__popcll(m1) + __popcll(m2) + __popcll(m3) + __popcll(m4));
        const ull mo = __ballot(kc > 4);
        const int wgid = blockIdx.x * 4 + wid;
        ull* kb = keys + ((size_t)b * WPI + wgid) * SLOTW;
        const int sc_ = (kc > 4) ? 4 : kc;
        if (sc_ >= 1 && pos + 0 < SLOTW) kb[pos + 0] = k0;
        if (sc_ >= 2 && pos + 1 < SLOTW) kb[pos + 1] = k1;
        if (sc_ >= 3 && pos + 2 < SLOTW) kb[pos + 2] = k2;
        if (sc_ >= 4 && pos + 3 < SLOTW) kb[pos + 3] = k3;
        const unsigned zstart = (tot > (unsigned)SLOTW) ? (unsigned)SLOTW : tot;
        if (lane >= 48) {
            const unsigned s = (unsigned)(lane - 48);
            if (s >= zstart) kb[s] = 0;
        }
        if (lane == 0)
            ovf_arr[b * WPI + wgid] = ((tot > (unsigned)SLOTW) || mo) ? 1u : 0u;
    }
    __syncthreads();   // drains all 4 waves' stores (vmcnt 0 at barrier)
    if (t == 0) {
        __threadfence();   // own dirty lines -> device visibility (cheap: few lines)
        // RELAXED add on a striped, cacheline-private counter: no per-add L2 writeback,
        // contention split 64 ways (16 stripes x 4 images)
        __hip_atomic_fetch_add(ctrp + (b * NSTR + (blockIdx.x & (NSTR - 1))) * 16, 1u,
                               __ATOMIC_RELAXED, __HIP_MEMORY_SCOPE_AGENT);
    }
    if (blockIdx.x != 0) return;              // only 4 tail blocks ever wait -> no deadlock
    if (t < NSTR) {
        while (__hip_atomic_load(ctrp + (b * NSTR + t) * 16, __ATOMIC_RELAXED,
                                 __HIP_MEMORY_SCOPE_AGENT) < (unsigned)(GBX / NSTR))
            __builtin_amdgcn_s_sleep(8);
    }
    if (t == 0)   // single acquire -> buffer_inv; key reads below see fresh data (R10-verified)
        (void)__hip_atomic_load(ctrp + b * NSTR * 16, __ATOMIC_ACQUIRE, __HIP_MEMORY_SCOPE_AGENT);
    __syncthreads();

    // ================= tail (1 block per image, 256 threads) =================
    ull* kb = keys + (size_t)b * KEYSPAN;

    // A: overflow reduce + tk init
    {
        unsigned o = 0;
        for (int i = t; i < WPI; i += 256) o |= ovf_arr[b * WPI + i];
        #pragma unroll
        for (int d = 32; d >= 1; d >>= 1) o |= __shfl_down(o, d);
        if (lane == 0) redo_[wid] = o;
    }
    for (int i = t; i < TOPN; i += 256) tkl[i] = 0;
    __syncthreads();
    if (t == 0) {
        dense_s = (redo_[0] | redo_[1] | redo_[2] | redo_[3]) ? 1 : 0;
        md_s = 0;
    }
    __syncthreads();
    if (dense_s) rebuild_(cls, ctr, kb, b, t, u.hist, &lpos, &cut_s, &md_s, &dense_s);

    // B/C: histogram + cutoff (retry once via rebuild if total < 512)
    for (int pass = 0; pass < 2; ++pass) {
        for (int i = t; i < SELBINS; i += 256) u.hist[i] = 0;
        if (t == 0) scnt = 0;
        __syncthreads();
        {
            const bool dn = (dense_s != 0);
            const int Md = md_s;
            for (int r = 0; r < KEYSPAN / 2048; ++r) {        // 16 rounds x 8 unrolled loads
                ull v[8];
                #pragma unroll
                for (int q = 0; q < 8; ++q) v[q] = kb[r * 2048 + q * 256 + t];
                #pragma unroll
                for (int q = 0; q < 8; ++q) {
                    const int g = r * 2048 + q * 256 + t;
                    const bool pred = dn ? (g < Md) : (v[q] != 0ull);
                    if (pred) atomicAdd(&u.hist[binof_(v[q], dn)], 1u);
                }
            }
        }
        __syncthreads();
        if (t < 64) {
            unsigned s = 0;
            #pragma unroll 8
            for (int i = 0; i < 64; ++i)
                s += u.hist[t * 64 + ((i + t) & 63)];
            unsigned suf = s;
            #pragma unroll
            for (int d = 1; d < 64; d <<= 1) {
                const unsigned o2 = __shfl_down(suf, d);
                suf += (t + d < 64) ? o2 : 0u;
            }
            if (t == 0) tot_s = suf;
            const ull mask = __ballot(suf >= TOPN);
            unsigned nxt = __shfl_down(suf, 1);
            if (t == 63) nxt = 0;
            if (mask == 0ull) {
                if (t == 0) cut_s = 0;
            } else {
                const int L = 63 - __builtin_clzll(mask);
                if (t == L) {
                    unsigned cum = nxt;
                    int c = L * 64;
                    for (int i = 63; i >= 0; --i) {
                        cum += u.hist[L * 64 + i];
                        if (cum >= TOPN) { c = L * 64 + i; break; }
                    }
                    cut_s = c;
                }
            }
        }
        __syncthreads();
        if (tot_s >= (unsigned)TOPN || dense_s) break;
        rebuild_(cls, ctr, kb, b, t, u.hist, &lpos, &cut_s, &md_s, &dense_s);
    }

    // D: wave-aggregated compact into surv (hist dead -> union reuse)
    {
        const bool dn = (dense_s != 0);
        const int Md = md_s;
        const int cb = cut_s;
        __syncthreads();
        for (int r = 0; r < KEYSPAN / 2048; ++r) {
            ull v[8];
            #pragma unroll
            for (int q = 0; q < 8; ++q) v[q] = kb[r * 2048 + q * 256 + t];
            #pragma unroll
            for (int q = 0; q < 8; ++q) {
                const int g = r * 2048 + q * 256 + t;
                bool pred = dn ? (g < Md) : (v[q] != 0ull);
                pred = pred && (binof_(v[q], dn) >= cb);
                const ull mv = __ballot(pred);
                unsigned base = 0;
                if (lane == 0 && mv) base = atomicAdd(&scnt, (unsigned)__popcll(mv));
                base = __shfl(base, 0);
                if (pred) {
                    const unsigned pos = base + (unsigned)__popcll(mv & lt);
                    if (pos < (unsigned)SCAP) u.surv[pos] = v[q];
                }
            }
        }
    }
    __syncthreads();

    // E: exact rank-count among survivors -> tkl (sorted desc)
    const unsigned sc_f = scnt;
    if (sc_f <= (unsigned)SCAP) {
        const int S = (int)sc_f;
        for (int i = t; i < S; i += 256) {
            const ull ke = u.surv[i];
            int r = 0;
            int j = 0;
            for (; j + 8 <= S; j += 8) {
                #pragma unroll
                for (int q = 0; q < 8; ++q) r += (u.surv[j + q] > ke) ? 1 : 0;
            }
            for (; j < S; ++j) r += (u.surv[j] > ke) ? 1 : 0;
            if (r < TOPN) tkl[r] = ke;
        }
    } else {
        // pathological tie storm: exact global rank-count (never on this data)
        const bool dn = (dense_s != 0);
        const int Md = md_s;
        for (int i = t; i < KEYSPAN; i += 256) {
            const ull k = kb[i];
            const bool v = dn ? (i < Md) : (k != 0ull);
            if (!v) continue;
            int r = 0;
            for (int j = 0; j < KEYSPAN; ++j) {
                const ull kj = kb[j];
                const bool vj = dn ? (j < Md) : (kj != 0ull);
                r += (vj && kj > k) ? 1 : 0;
            }
            if (r < TOPN) tkl[r] = k;
        }
    }
    __syncthreads();

    // F: decode (2 slots/thread; surv dead -> nms union live)
    #pragma unroll
    for (int half = 0; half < 2; ++half) {
        const int s_ = half * 256 + t;
        const ull k = tkl[s_];
        const unsigned bits = (unsigned)(k >> 32);
        const float val = __uint_as_float(bits);
        const unsigned flat = ~(unsigned)(k & 0xffffffffu);
        int n = 0, c = 0;
        if (val > 0.0f) { n = (int)(flat >> 3); c = (int)(flat & 7u); }
        const float lx = loc[n * 3 + 0], ly = loc[n * 3 + 1], lz = loc[n * 3 + 2];
        const float* bp = box + (size_t)b * 6 * NLOC + n;
        const float b0 = bp[0];
        const float b1 = bp[(size_t)NLOC];
        const float b2 = bp[2 * (size_t)NLOC];
        const float b3 = bp[3 * (size_t)NLOC];
        const float b4 = bp[4 * (size_t)NLOC];
        const float b5 = bp[5 * (size_t)NLOC];
        const float d0 = fminf(fmaxf(lx - b0, 0.0f), 255.0f);
        const float d1 = fminf(fmaxf(ly - b1, 0.0f), 255.0f);
        const float d2 = fminf(fmaxf(lz - b2, 0.0f), 63.0f);
        const float d3 = fminf(fmaxf(lx + b3, 0.0f), 255.0f);
        const float d4 = fminf(fmaxf(ly + b4, 0.0f), 255.0f);
        const float d5 = fminf(fmaxf(lz + b5, 0.0f), 63.0f);
        const bool ok = (d3 - d0 >= 0.0f) && (d4 - d1 >= 0.0f) && (d5 - d2 >= 0.0f);
        u.nms.sd[s_ * 6 + 0] = d0; u.nms.sd[s_ * 6 + 1] = d1; u.nms.sd[s_ * 6 + 2] = d2;
        u.nms.sd[s_ * 6 + 3] = d3; u.nms.sd[s_ * 6 + 4] = d4; u.nms.sd[s_ * 6 + 5] = d5;
        u.nms.ss[s_] = (val > 0.0f) ? sqrtf(val) : 0.0f;
        u.nms.scl[s_] = (unsigned char)(c + 1);
        u.nms.keep[s_] = ((val > 0.0f) && ok) ? 1 : 0;
    }
    __syncthreads();

    // G: per-class NMS; wave w handles classes w+1 and w+5
    for (int qq = 0; qq < 2; ++qq) {
        const int mycls = wid + 1 + 4 * qq;
        const float* sd = u.nms.sd;
        int cnt = 0;
        for (int j0 = 0; j0 < TOPN; j0 += 64) {
            const int j = j0 + lane;
            const bool pred = ((int)u.nms.scl[j] == mycls) && (u.nms.keep[j] != 0);
            const ull m = __ballot(pred);
            if (pred) {
                const int pos = cnt + __popcll(m & lt);
                if (pos < 128) u.nms.clist[wid][pos] = (short)j;
            }
            cnt += __popcll(m);
        }
        if (cnt <= 128) {
            const bool h0 = (lane < cnt), h1 = (lane + 64 < cnt);
            const int g0 = h0 ? u.nms.clist[wid][lane] : 0;
            const int g1 = h1 ? u.nms.clist[wid][lane + 64] : 0;
            float A0[6], A1[6];
            #pragma unroll
            for (int q = 0; q < 6; ++q) {
                A0[q] = h0 ? sd[g0 * 6 + q] : 0.0f;
                A1[q] = h1 ? sd[g1 * 6 + q] : 0.0f;
            }
            ull s0 = 0, s1lo = 0, s1hi = 0;
            for (int i = 0; i < cnt; ++i) {
                const int gi = u.nms.clist[wid][i];
                float pb[6];
                #pragma unroll
                for (int q = 0; q < 6; ++q) pb[q] = sd[gi * 6 + q];
                if (i < 64) {
                    if (h0 && lane > i && iou3d_(A0, pb) > NMS_THR) s0 |= 1ull << i;
                    if (h1 && iou3d_(A1, pb) > NMS_THR) s1lo |= 1ull << i;
                } else {
                    if (h1 && (i - 64) < lane && iou3d_(A1, pb) > NMS_THR) s1hi |= 1ull << (i - 64);
                }
            }
            bool a0 = h0, a1 = h1;
            ull m0 = __ballot(a0), m1 = __ballot(a1);
            for (int i = 0; i < cnt; ++i) {
                const bool alive_i = (i < 64) ? ((m0 >> i) & 1ull) : ((m1 >> (i - 64)) & 1ull);
                if (!alive_i) continue;
                if (a0 && i < 64 && ((s0 >> i) & 1ull)) a0 = false;
                if (a1) {
                    const bool sb = (i < 64) ? ((s1lo >> i) & 1ull) : ((s1hi >> (i - 64)) & 1ull);
                    if (sb) a1 = false;
                }
                m0 = __ballot(a0); m1 = __ballot(a1);
            }
            if (h0 && !a0) u.nms.keep[g0] = 0;
            if (h1 && !a1) u.nms.keep[g1] = 0;
        } else {
            // general greedy over raw slots (adversarial class skew only)
            volatile unsigned char* vkeep = u.nms.keep;
            for (int i = 0; i < TOPN; ++i) {
                if ((int)u.nms.scl[i] != mycls || !vkeep[i]) continue;
                float pb[6];
                #pragma unroll
                for (int q = 0; q < 6; ++q) pb[q] = sd[i * 6 + q];
                for (int e = i + 1 + lane; e < TOPN; e += 64) {
                    if ((int)u.nms.scl[e] == mycls && vkeep[e]) {
                        float cbx[6];
                        #pragma unroll
                        for (int q = 0; q < 6; ++q) cbx[q] = sd[e * 6 + q];
                        if (iou3d_(cbx, pb) > NMS_THR) vkeep[e] = 0;
                    }
                }
                __threadfence_block();
            }
        }
    }
    __syncthreads();

    // H: rank survivors in slot order, emit top-100
    #pragma unroll
    for (int half = 0; half < 2; ++half) {
        const int s_ = half * 256 + t;
        const ull m = __ballot(u.nms.keep[s_] != 0);
        if (lane == 0) chcnt[half * 4 + wid] = __popcll(m);
    }
    __syncthreads();
    {
        int total = 0;
        #pragma unroll
        for (int c = 0; c < NC; ++c) total += chcnt[c];
        const int tc = (total < POST) ? total : POST;
        float* fbox = out;                       // (B,100,6)
        float* fscore = out + NB * POST * 6;     // (B,100)
        float* flabel = out + NB * POST * 7;     // (B,100)
        float* fvalid = out + NB * POST * 8;     // (B,100)
        #pragma unroll
        for (int half = 0; half < 2; ++half) {
            const int s_ = half * 256 + t;
            const int chunk = half * 4 + wid;
            const ull m = __ballot(u.nms.keep[s_] != 0);
            int before = 0;
            for (int c = 0; c < chunk; ++c) before += chcnt[c];
            const int myrank = before + __popcll(m & lt);
            if (u.nms.keep[s_] && myrank < POST) {
                #pragma unroll
                for (int q = 0; q < 6; ++q)
                    fbox[(b * POST + myrank) * 6 + q] = u.nms.sd[s_ * 6 + q];
                fscore[b * POST + myrank] = u.nms.ss[s_];
                flabel[b * POST + myrank] = (float)u.nms.scl[s_];
                fvalid[b * POST + myrank] = 1.0f;
            }
            if (s_ >= tc && s_ < POST) {
                #pragma unroll
                for (int q = 0; q < 6; ++q) fbox[(b * POST + s_) * 6 + q] = 0.0f;
                fscore[b * POST + s_] = 0.0f;
                flabel[b * POST + s_] = 0.0f;
                fvalid[b * POST + s_] = 0.0f;
            }
        }
    }
}

extern "C" void kernel_launch(void* const* d_in, const int* in_sizes, int n_in,
                              void* d_out, int out_size, void* d_ws, size_t ws_size,
                              hipStream_t stream) {
    const float* location = (const float*)d_in[0];
    const float* cls_pred = (const float*)d_in[1];
    const float* box_pred = (const float*)d_in[2];
    const float* ctr_pred = (const float*)d_in[3];

    char* ws = (char*)d_ws;
    unsigned* ctrp = (unsigned*)(ws + OFF_CTR);
    unsigned* ovf  = (unsigned*)(ws + OFF_OVF);
    ull*      keys = (ull*)(ws + OFF_KEYS);

    hipMemsetAsync(ws + OFF_CTR, 0, 4096, stream);
    fused_all<<<dim3(GBX, NB), 256, 0, stream>>>(cls_pred, ctr_pred, location, box_pred,
                                                 keys, ovf, ctrp, (float*)d_out);
}

// Round 12
// 149.729 us; speedup vs baseline: 1.6359x; 1.3603x over previous
//
#include <hip/hip_runtime.h>

#define NB 4
#define NC 8
#define NLOC 524288        // H*W*D
#define TOPN 512
#define POST 100
#define SELBINS 4096
#define SCAP 2048
#define GBX 512            // gather blocks per image
#define WPI 2048           // waves per image
#define SLOTW 16
#define KEYSPAN (WPI*SLOTW)   // 32768 keys/image
#define FB_CAP 16384
#define NMS_THR 0.6f
#define CAND_THR 0.05f

typedef unsigned long long ull;

// ---------------- workspace (fully rewritten each call; NO memset) ----------------
// [0, NB*WPI*4)                    ovf_arr
// [32768, 32768+NB*KEYSPAN*8)      keys (zero-sentinel padded per wave slot)
#define OFF_OVF  0
#define OFF_KEYS 32768

__device__ __forceinline__ float sigmoidf_(float x) {
    return 1.0f / (1.0f + __expf(-x));
}

// sparse keys: score>0.5 -> hi in (0x3F000000,0x3F800000]; dense (fallback): >0.05
__device__ __forceinline__ int binof_(ull k, bool dn) {
    const unsigned hi = (unsigned)(k >> 32);
    const int off = (int)hi - (dn ? 0x3D000000 : 0x3F000000);
    int bin = dn ? (off >> 14) : (off >> 11);
    if (off < 0) bin = 0;
    if (bin > SELBINS - 1) bin = SELBINS - 1;
    return bin;
}

__device__ __forceinline__ float iou3d_(const float* a, const float* bx) {
    const float ix = fminf(a[3], bx[3]) - fmaxf(a[0], bx[0]);
    const float iy = fminf(a[4], bx[4]) - fmaxf(a[1], bx[1]);
    const float iz = fminf(a[5], bx[5]) - fmaxf(a[2], bx[2]);
    const float inter = fmaxf(ix, 0.0f) * fmaxf(iy, 0.0f) * fmaxf(iz, 0.0f);
    const float v0 = fmaxf(a[3] - a[0], 0.0f) * fmaxf(a[4] - a[1], 0.0f) * fmaxf(a[5] - a[2], 0.0f);
    const float v1 = fmaxf(bx[3] - bx[0], 0.0f) * fmaxf(bx[4] - bx[1], 0.0f) * fmaxf(bx[5] - bx[2], 0.0f);
    return inter / (v0 + v1 - inter + 1e-9f);
}

// ---------------- Pass 1: gather — no LDS, no atomics, no barriers (R9-proven) ----------------
__global__ __launch_bounds__(256) void gather_spec(const float* __restrict__ cls,
                                                   const float* __restrict__ ctr,
                                                   ull* __restrict__ keys,
                                                   unsigned* __restrict__ ovf_arr) {
    const int b = blockIdx.y;
    const int t = threadIdx.x, lane = t & 63, wid = t >> 6;
    const int n0 = (blockIdx.x * 256 + t) * 4;

    const float4 cv = *(const float4*)(ctr + (size_t)b * NLOC + n0);
    float4 cl[NC];
    #pragma unroll
    for (int c = 0; c < NC; ++c)
        cl[c] = *(const float4*)(cls + ((size_t)b * NC + c) * NLOC + n0);

    unsigned hm = 0;
    #pragma unroll
    for (int j = 0; j < 4; ++j)
        #pragma unroll
        for (int c = 0; c < NC; ++c)
            if (((const float*)&cl[c])[j] > 0.0f) hm |= 1u << (j * 8 + c);

    ull k0 = 0, k1 = 0, k2 = 0, k3 = 0;
    int kc = 0;
    if (hm) {                                  // ~4.7% of lanes
        #pragma unroll
        for (int j = 0; j < 4; ++j) {
            if ((hm >> (j * 8)) & 0xffu) {
                const float sc = sigmoidf_(((const float*)&cv)[j]);
                #pragma unroll
                for (int c = 0; c < NC; ++c) {
                    if ((hm >> (j * 8 + c)) & 1u) {
                        const float p = sigmoidf_(((const float*)&cl[c])[j]) * sc;
                        if (p > 0.5f) {
                            const unsigned flat = (unsigned)((n0 + j) * NC + c);
                            const ull key = ((ull)__float_as_uint(p) << 32) | (unsigned)(~flat);
                            if (kc == 0) k0 = key;
                            else if (kc == 1) k1 = key;
                            else if (kc == 2) k2 = key;
                            else if (kc == 3) k3 = key;
                            ++kc;
                        }
                    }
                }
            }
        }
    }
    const ull m1 = __ballot(kc >= 1), m2 = __ballot(kc >= 2);
    const ull m3 = __ballot(kc >= 3), m4 = __ballot(kc >= 4);
    const ull lt = (1ull << lane) - 1ull;
    const unsigned pos = (unsigned)(__popcll(m1 & lt) + __popcll(m2 & lt) +
                                    __popcll(m3 & lt) + __popcll(m4 & lt));
    const unsigned tot = (unsigned)(__popcll(m1) + __popcll(m2) + __popcll(m3) + __popcll(m4));
    const ull mo = __ballot(kc > 4);
    const int wgid = blockIdx.x * 4 + wid;
    ull* kb = keys + ((size_t)b * WPI + wgid) * SLOTW;
    const int sc_ = (kc > 4) ? 4 : kc;
    if (sc_ >= 1 && pos + 0 < SLOTW) kb[pos + 0] = k0;
    if (sc_ >= 2 && pos + 1 < SLOTW) kb[pos + 1] = k1;
    if (sc_ >= 3 && pos + 2 < SLOTW) kb[pos + 2] = k2;
    if (sc_ >= 4 && pos + 3 < SLOTW) kb[pos + 3] = k3;
    const unsigned zstart = (tot > (unsigned)SLOTW) ? (unsigned)SLOTW : tot;
    if (lane >= 48) {
        const unsigned s = (unsigned)(lane - 48);
        if (s >= zstart) kb[s] = 0;
    }
    if (lane == 0)
        ovf_arr[b * WPI + wgid] = ((tot > (unsigned)SLOTW) || mo) ? 1u : 0u;
}

// exact fallback rebuild (block-uniform; ~never runs). 256-thread version.
__device__ void rebuild_(const float* __restrict__ cls, const float* __restrict__ ctr,
                         ull* __restrict__ kb, int b, int t,
                         unsigned* hist, unsigned* lpos, int* cut_s, int* md_s, int* dense_s) {
    for (int i = t; i < SELBINS; i += 256) hist[i] = 0;
    if (t == 0) *lpos = 0;
    __syncthreads();
    for (int n = t; n < NLOC; n += 256) {
        const float scv = sigmoidf_(ctr[(size_t)b * NLOC + n]);
        #pragma unroll
        for (int cc = 0; cc < NC; ++cc) {
            const float x = cls[((size_t)b * NC + cc) * NLOC + n];
            if (x > -2.9444390f) {                        // sigmoid(x) > 0.05 pre-gate
                const float s = sigmoidf_(x);
                if (s > CAND_THR) {
                    const ull key = ((ull)__float_as_uint(s * scv) << 32) |
                                    (unsigned)(~(unsigned)(n * NC + cc));
                    atomicAdd(&hist[binof_(key, true)], 1u);
                }
            }
        }
    }
    __syncthreads();
    if (t == 0) {
        unsigned cum = 0; int bin = 0;
        for (int i = SELBINS - 1; i >= 0; --i) {
            cum += hist[i];
            if (cum >= (unsigned)TOPN) { bin = i; break; }
        }
        *cut_s = bin;
    }
    __syncthreads();
    const int cb = *cut_s;
    for (int n = t; n < NLOC; n += 256) {
        const float scv = sigmoidf_(ctr[(size_t)b * NLOC + n]);
        #pragma unroll
        for (int cc = 0; cc < NC; ++cc) {
            const float x = cls[((size_t)b * NC + cc) * NLOC + n];
            if (x > -2.9444390f) {
                const float s = sigmoidf_(x);
                if (s > CAND_THR) {
                    const ull key = ((ull)__float_as_uint(s * scv) << 32) |
                                    (unsigned)(~(unsigned)(n * NC + cc));
                    if (binof_(key, true) >= cb) {
                        const unsigned pos = atomicAdd(lpos, 1u);
                        if (pos < (unsigned)FB_CAP) kb[pos] = key;
                    }
                }
            }
        }
    }
    __syncthreads();
    if (t == 0) {
        *md_s = (int)((*lpos < (unsigned)FB_CAP) ? *lpos : (unsigned)FB_CAP);
        *dense_s = 1;
    }
    __syncthreads();
}

// ---------------- Pass 2: tail — 256 threads/block, 1 block/image (no VGPR cap) ----------------
__global__ __launch_bounds__(256) void select_nms(const float* __restrict__ cls,
                                                  const float* __restrict__ ctr,
                                                  const float* __restrict__ loc,
                                                  const float* __restrict__ box,
                                                  ull* __restrict__ keys,
                                                  const unsigned* __restrict__ ovf_arr,
                                                  float* __restrict__ out) {
    __shared__ union SU {
        unsigned hist[SELBINS];                                   // 16KB (select + rebuild)
        ull surv[SCAP];                                           // 16KB
        struct { float sd[TOPN * 6]; float ss[TOPN];
                 unsigned char scl[TOPN]; unsigned char keep[TOPN];
                 short clist[NC][128]; } nms;                     // ~17KB
    } u;
    __shared__ ull tkl[TOPN];                                     // 4KB
    __shared__ unsigned redo_[4];
    __shared__ unsigned scnt, tot_s, lpos;
    __shared__ int cut_s, dense_s, md_s, chcnt[NC];

    const int b = blockIdx.x;
    const int t = threadIdx.x, lane = t & 63, wid = t >> 6;
    const ull lt = (1ull << lane) - 1ull;
    ull* kb = keys + (size_t)b * KEYSPAN;

    // A: overflow reduce + tk init
    {
        unsigned o = 0;
        for (int i = t; i < WPI; i += 256) o |= ovf_arr[b * WPI + i];
        #pragma unroll
        for (int d = 32; d >= 1; d >>= 1) o |= __shfl_down(o, d);
        if (lane == 0) redo_[wid] = o;
    }
    for (int i = t; i < TOPN; i += 256) tkl[i] = 0;
    __syncthreads();
    if (t == 0) {
        dense_s = (redo_[0] | redo_[1] | redo_[2] | redo_[3]) ? 1 : 0;
        md_s = 0;
    }
    __syncthreads();
    if (dense_s) rebuild_(cls, ctr, kb, b, t, u.hist, &lpos, &cut_s, &md_s, &dense_s);

    // B/C: histogram + cutoff (retry once via rebuild if total < 512)
    for (int pass = 0; pass < 2; ++pass) {
        for (int i = t; i < SELBINS; i += 256) u.hist[i] = 0;
        if (t == 0) scnt = 0;
        __syncthreads();
        {
            const bool dn = (dense_s != 0);
            const int Md = md_s;
            for (int r = 0; r < KEYSPAN / 2048; ++r) {        // 16 rounds x 8 batched loads
                ull v[8];
                #pragma unroll
                for (int q = 0; q < 8; ++q) v[q] = kb[r * 2048 + q * 256 + t];
                #pragma unroll
                for (int q = 0; q < 8; ++q) {
                    const int g = r * 2048 + q * 256 + t;
                    const bool pred = dn ? (g < Md) : (v[q] != 0ull);
                    if (pred) atomicAdd(&u.hist[binof_(v[q], dn)], 1u);
                }
            }
        }
        __syncthreads();
        if (t < 64) {
            unsigned s = 0;
            #pragma unroll 8
            for (int i = 0; i < 64; ++i)
                s += u.hist[t * 64 + ((i + t) & 63)];
            unsigned suf = s;
            #pragma unroll
            for (int d = 1; d < 64; d <<= 1) {
                const unsigned o2 = __shfl_down(suf, d);
                suf += (t + d < 64) ? o2 : 0u;
            }
            if (t == 0) tot_s = suf;
            const ull mask = __ballot(suf >= TOPN);
            unsigned nxt = __shfl_down(suf, 1);
            if (t == 63) nxt = 0;
            if (mask == 0ull) {
                if (t == 0) cut_s = 0;
            } else {
                const int L = 63 - __builtin_clzll(mask);
                if (t == L) {
                    unsigned cum = nxt;
                    int c = L * 64;
                    for (int i = 63; i >= 0; --i) {
                        cum += u.hist[L * 64 + i];
                        if (cum >= TOPN) { c = L * 64 + i; break; }
                    }
                    cut_s = c;
                }
            }
        }
        __syncthreads();
        if (tot_s >= (unsigned)TOPN || dense_s) break;
        rebuild_(cls, ctr, kb, b, t, u.hist, &lpos, &cut_s, &md_s, &dense_s);
    }

    // D: wave-aggregated compact into surv (hist dead -> union reuse)
    {
        const bool dn = (dense_s != 0);
        const int Md = md_s;
        const int cb = cut_s;
        __syncthreads();
        for (int r = 0; r < KEYSPAN / 2048; ++r) {
            ull v[8];
            #pragma unroll
            for (int q = 0; q < 8; ++q) v[q] = kb[r * 2048 + q * 256 + t];
            #pragma unroll
            for (int q = 0; q < 8; ++q) {
                const int g = r * 2048 + q * 256 + t;
                bool pred = dn ? (g < Md) : (v[q] != 0ull);
                pred = pred && (binof_(v[q], dn) >= cb);
                const ull mv = __ballot(pred);
                unsigned base = 0;
                if (lane == 0 && mv) base = atomicAdd(&scnt, (unsigned)__popcll(mv));
                base = __shfl(base, 0);
                if (pred) {
                    const unsigned pos = base + (unsigned)__popcll(mv & lt);
                    if (pos < (unsigned)SCAP) u.surv[pos] = v[q];
                }
            }
        }
    }
    __syncthreads();

    // E: exact rank-count among survivors -> tkl (sorted desc)
    const unsigned sc_f = scnt;
    if (sc_f <= (unsigned)SCAP) {
        const int S = (int)sc_f;
        for (int i = t; i < S; i += 256) {
            const ull ke = u.surv[i];
            int r = 0;
            int j = 0;
            for (; j + 8 <= S; j += 8) {
                #pragma unroll
                for (int q = 0; q < 8; ++q) r += (u.surv[j + q] > ke) ? 1 : 0;
            }
            for (; j < S; ++j) r += (u.surv[j] > ke) ? 1 : 0;
            if (r < TOPN) tkl[r] = ke;
        }
    } else {
        // pathological tie storm: exact global rank-count (never on this data)
        const bool dn = (dense_s != 0);
        const int Md = md_s;
        for (int i = t; i < KEYSPAN; i += 256) {
            const ull k = kb[i];
            const bool v = dn ? (i < Md) : (k != 0ull);
            if (!v) continue;
            int r = 0;
            for (int j = 0; j < KEYSPAN; ++j) {
                const ull kj = kb[j];
                const bool vj = dn ? (j < Md) : (kj != 0ull);
                r += (vj && kj > k) ? 1 : 0;
            }
            if (r < TOPN) tkl[r] = k;
        }
    }
    __syncthreads();

    // F: decode (2 slots/thread; surv dead -> nms union live)
    #pragma unroll
    for (int half = 0; half < 2; ++half) {
        const int s_ = half * 256 + t;
        const ull k = tkl[s_];
        const unsigned bits = (unsigned)(k >> 32);
        const float val = __uint_as_float(bits);
        const unsigned flat = ~(unsigned)(k & 0xffffffffu);
        int n = 0, c = 0;
        if (val > 0.0f) { n = (int)(flat >> 3); c = (int)(flat & 7u); }
        const float lx = loc[n * 3 + 0], ly = loc[n * 3 + 1], lz = loc[n * 3 + 2];
        const float* bp = box + (size_t)b * 6 * NLOC + n;
        const float b0 = bp[0];
        const float b1 = bp[(size_t)NLOC];
        const float b2 = bp[2 * (size_t)NLOC];
        const float b3 = bp[3 * (size_t)NLOC];
        const float b4 = bp[4 * (size_t)NLOC];
        const float b5 = bp[5 * (size_t)NLOC];
        const float d0 = fminf(fmaxf(lx - b0, 0.0f), 255.0f);
        const float d1 = fminf(fmaxf(ly - b1, 0.0f), 255.0f);
        const float d2 = fminf(fmaxf(lz - b2, 0.0f), 63.0f);
        const float d3 = fminf(fmaxf(lx + b3, 0.0f), 255.0f);
        const float d4 = fminf(fmaxf(ly + b4, 0.0f), 255.0f);
        const float d5 = fminf(fmaxf(lz + b5, 0.0f), 63.0f);
        const bool ok = (d3 - d0 >= 0.0f) && (d4 - d1 >= 0.0f) && (d5 - d2 >= 0.0f);
        u.nms.sd[s_ * 6 + 0] = d0; u.nms.sd[s_ * 6 + 1] = d1; u.nms.sd[s_ * 6 + 2] = d2;
        u.nms.sd[s_ * 6 + 3] = d3; u.nms.sd[s_ * 6 + 4] = d4; u.nms.sd[s_ * 6 + 5] = d5;
        u.nms.ss[s_] = (val > 0.0f) ? sqrtf(val) : 0.0f;
        u.nms.scl[s_] = (unsigned char)(c + 1);
        u.nms.keep[s_] = ((val > 0.0f) && ok) ? 1 : 0;
    }
    __syncthreads();

    // G: per-class NMS; wave w handles classes w+1 and w+5
    for (int qq = 0; qq < 2; ++qq) {
        const int mycls = wid + 1 + 4 * qq;
        const float* sd = u.nms.sd;
        int cnt = 0;
        for (int j0 = 0; j0 < TOPN; j0 += 64) {
            const int j = j0 + lane;
            const bool pred = ((int)u.nms.scl[j] == mycls) && (u.nms.keep[j] != 0);
            const ull m = __ballot(pred);
            if (pred) {
                const int pos = cnt + __popcll(m & lt);
                if (pos < 128) u.nms.clist[wid][pos] = (short)j;
            }
            cnt += __popcll(m);
        }
        if (cnt <= 128) {
            const bool h0 = (lane < cnt), h1 = (lane + 64 < cnt);
            const int g0 = h0 ? u.nms.clist[wid][lane] : 0;
            const int g1 = h1 ? u.nms.clist[wid][lane + 64] : 0;
            float A0[6], A1[6];
            #pragma unroll
            for (int q = 0; q < 6; ++q) {
                A0[q] = h0 ? sd[g0 * 6 + q] : 0.0f;
                A1[q] = h1 ? sd[g1 * 6 + q] : 0.0f;
            }
            ull s0 = 0, s1lo = 0, s1hi = 0;
            for (int i = 0; i < cnt; ++i) {
                const int gi = u.nms.clist[wid][i];
                float pb[6];
                #pragma unroll
                for (int q = 0; q < 6; ++q) pb[q] = sd[gi * 6 + q];
                if (i < 64) {
                    if (h0 && lane > i && iou3d_(A0, pb) > NMS_THR) s0 |= 1ull << i;
                    if (h1 && iou3d_(A1, pb) > NMS_THR) s1lo |= 1ull << i;
                } else {
                    if (h1 && (i - 64) < lane && iou3d_(A1, pb) > NMS_THR) s1hi |= 1ull << (i - 64);
                }
            }
            bool a0 = h0, a1 = h1;
            ull m0 = __ballot(a0), m1 = __ballot(a1);
            for (int i = 0; i < cnt; ++i) {
                const bool alive_i = (i < 64) ? ((m0 >> i) & 1ull) : ((m1 >> (i - 64)) & 1ull);
                if (!alive_i) continue;
                if (a0 && i < 64 && ((s0 >> i) & 1ull)) a0 = false;
                if (a1) {
                    const bool sb = (i < 64) ? ((s1lo >> i) & 1ull) : ((s1hi >> (i - 64)) & 1ull);
                    if (sb) a1 = false;
                }
                m0 = __ballot(a0); m1 = __ballot(a1);
            }
            if (h0 && !a0) u.nms.keep[g0] = 0;
            if (h1 && !a1) u.nms.keep[g1] = 0;
        } else {
            // general greedy over raw slots (adversarial class skew only)
            volatile unsigned char* vkeep = u.nms.keep;
            for (int i = 0; i < TOPN; ++i) {
                if ((int)u.nms.scl[i] != mycls || !vkeep[i]) continue;
                float pb[6];
                #pragma unroll
                for (int q = 0; q < 6; ++q) pb[q] = sd[i * 6 + q];
                for (int e = i + 1 + lane; e < TOPN; e += 64) {
                    if ((int)u.nms.scl[e] == mycls && vkeep[e]) {
                        float cbx[6];
                        #pragma unroll
                        for (int q = 0; q < 6; ++q) cbx[q] = sd[e * 6 + q];
                        if (iou3d_(cbx, pb) > NMS_THR) vkeep[e] = 0;
                    }
                }
                __threadfence_block();
            }
        }
    }
    __syncthreads();

    // H: rank survivors in slot order, emit top-100
    #pragma unroll
    for (int half = 0; half < 2; ++half) {
        const int s_ = half * 256 + t;
        const ull m = __ballot(u.nms.keep[s_] != 0);
        if (lane == 0) chcnt[half * 4 + wid] = __popcll(m);
    }
    __syncthreads();
    {
        int total = 0;
        #pragma unroll
        for (int c = 0; c < NC; ++c) total += chcnt[c];
        const int tc = (total < POST) ? total : POST;
        float* fbox = out;                       // (B,100,6)
        float* fscore = out + NB * POST * 6;     // (B,100)
        float* flabel = out + NB * POST * 7;     // (B,100)
        float* fvalid = out + NB * POST * 8;     // (B,100)
        #pragma unroll
        for (int half = 0; half < 2; ++half) {
            const int s_ = half * 256 + t;
            const int chunk = half * 4 + wid;
            const ull m = __ballot(u.nms.keep[s_] != 0);
            int before = 0;
            for (int c = 0; c < chunk; ++c) before += chcnt[c];
            const int myrank = before + __popcll(m & lt);
            if (u.nms.keep[s_] && myrank < POST) {
                #pragma unroll
                for (int q = 0; q < 6; ++q)
                    fbox[(b * POST + myrank) * 6 + q] = u.nms.sd[s_ * 6 + q];
                fscore[b * POST + myrank] = u.nms.ss[s_];
                flabel[b * POST + myrank] = (float)u.nms.scl[s_];
                fvalid[b * POST + myrank] = 1.0f;
            }
            if (s_ >= tc && s_ < POST) {
                #pragma unroll
                for (int q = 0; q < 6; ++q) fbox[(b * POST + s_) * 6 + q] = 0.0f;
                fscore[b * POST + s_] = 0.0f;
                flabel[b * POST + s_] = 0.0f;
                fvalid[b * POST + s_] = 0.0f;
            }
        }
    }
}

extern "C" void kernel_launch(void* const* d_in, const int* in_sizes, int n_in,
                              void* d_out, int out_size, void* d_ws, size_t ws_size,
                              hipStream_t stream) {
    const float* location = (const float*)d_in[0];
    const float* cls_pred = (const float*)d_in[1];
    const float* box_pred = (const float*)d_in[2];
    const float* ctr_pred = (const float*)d_in[3];

    char* ws = (char*)d_ws;
    unsigned* ovf  = (unsigned*)(ws + OFF_OVF);
    ull*      keys = (ull*)(ws + OFF_KEYS);

    gather_spec<<<dim3(GBX, NB), 256, 0, stream>>>(cls_pred, ctr_pred, keys, ovf);
    select_nms<<<NB, 256, 0, stream>>>(cls_pred, ctr_pred, location, box_pred,
                                       keys, ovf, (float*)d_out);
}